// Round 10
// baseline (1295.871 us; speedup 1.0000x reference)
//
#include <hip/hip_runtime.h>
#include <hip/hip_fp16.h>

#define TN 64
#define BN 2048
#define G 4
#define NBLK (BN / G)   // 512 blocks x 512 threads, target 2 blocks/CU

typedef _Float16 h2v __attribute__((ext_vector_type(2)));
typedef _Float16 half8 __attribute__((ext_vector_type(8)));
typedef float float4v __attribute__((ext_vector_type(4)));

union FU {
    uint4 u;
    half8 h8;
    h2v hv[4];
    __half2 h2[4];
    _Float16 f16[8];
};
union H2U { __half2 h; h2v v; };

#define LAUNDER4(v) asm volatile("" : "+v"((v).x), "+v"((v).y), "+v"((v).z), "+v"((v).w))

__device__ __forceinline__ float fast_sigmoid(float x) {
    return __builtin_amdgcn_rcpf(1.f + __expf(-x));
}
__device__ __forceinline__ float fast_tanhf(float x) {
    return fmaf(2.f, fast_sigmoid(2.f * x), -1.f);
}
__device__ __forceinline__ float fdot2f(__half2 a, __half2 b, float c) {
    H2U ua; ua.h = a; H2U ub; ub.h = b;
    return __builtin_amdgcn_fdot2(ua.v, ub.v, c, false);
}
// packed fp16 tanh: t=2^(k*x)=e^{-2x}; r=1/(1+t)=sigmoid(2x); tanh=2r-1
__device__ __forceinline__ __half2 tanh2(__half2 x, __half2 kk, __half2 one2,
                                         __half2 two2, __half2 none2) {
    __half2 tv = h2exp2(__hmul2(x, kk));
    __half2 r = h2rcp(__hadd2(tv, one2));
    return __hfma2(two2, r, none2);
}

// dc swizzled offset (halves): chunk c of row g at slot (c&16)|((c&15)^g)
__device__ __forceinline__ int dc_off(int g, int e) {
    int c = e >> 3;
    int slot = (c & 16) | ((c & 15) ^ (g & 15));
    return g * 256 + slot * 8 + (e & 7);
}

// ---- HW[b,t,f] = H[b,t,:] @ W1[256:384,:] + b1, fp16 linear [b*T+t][128]
__global__ __launch_bounds__(256) void prep_hw(
    const float* __restrict__ H, const float* __restrict__ W1,
    const float* __restrict__ b1, __half* __restrict__ HWh) {
    __shared__ float sH[16 * 128];
    const int i = threadIdx.x;
    const long r0 = (long)blockIdx.x * 16;
    #pragma unroll
    for (int u = 0; u < 8; ++u) sH[u * 256 + i] = H[r0 * 128 + u * 256 + i];
    __syncthreads();
    const int f = i & 127;
    const int half_ = i >> 7;
    float acc[8];
    float bb = b1[f];
    #pragma unroll
    for (int u = 0; u < 8; ++u) acc[u] = bb;
    #pragma unroll 4
    for (int h = 0; h < 128; ++h) {
        float wv = W1[(256 + h) * 128 + f];
        #pragma unroll
        for (int u = 0; u < 8; ++u)
            acc[u] = fmaf(sH[(half_ + 2 * u) * 128 + h], wv, acc[u]);
    }
    #pragma unroll
    for (int u = 0; u < 8; ++u)
        HWh[(r0 + half_ + 2 * u) * 128 + f] = __float2half(acc[u]);
}

// ---- HhT[b][f][t] = fp16(H[b][t][f])
__global__ __launch_bounds__(256) void prep_ht(
    const float* __restrict__ H, __half* __restrict__ HhT) {
    __shared__ __half sh[64 * 128];
    const int b = blockIdx.x, i = threadIdx.x;
    #pragma unroll
    for (int u = 0; u < 32; ++u) {
        int idx = u * 256 + i;
        sh[idx] = __float2half(H[(long)b * 8192 + idx]);
    }
    __syncthreads();
    const int f = i >> 1, t0 = (i & 1) * 32;
    __half* ob = HhT + (long)b * 8192 + (long)i * 32;
    #pragma unroll
    for (int k = 0; k < 32; ++k) ob[k] = sh[(t0 + k) * 128 + f];
}

// ---- W1m: W1[0:256][:] in MFMA B-frag layout (frag fi = w*8+kt)
__global__ __launch_bounds__(256) void prep_w1m(
    const float* __restrict__ W1, __half* __restrict__ W1m) {
    int tid = blockIdx.x * 256 + threadIdx.x;   // 32768
    int fi = tid >> 9, rem = tid & 511, l = rem >> 3, j = rem & 7;
    int w = fi >> 3, kt = fi & 7;
    int row = kt * 32 + (l >> 4) * 8 + j;
    int col = w * 16 + (l & 15);
    W1m[tid] = __float2half(W1[row * 128 + col]);
}

// ---- WTm: Whh^T in MFMA B-frag layout (frag fi = nt*4+kt)
__global__ __launch_bounds__(256) void prep_wtm(
    const float* __restrict__ Whh, __half* __restrict__ WTm) {
    int tid = blockIdx.x * 256 + threadIdx.x;   // 65536
    int fi = tid >> 9, rem = tid & 511, l = rem >> 3, j = rem & 7;
    int nt = fi >> 2, kt = fi & 3;
    int k = kt * 32 + (l >> 4) * 8 + j;
    int n = nt * 16 + (l & 15);
    WTm[tid] = __float2half(Whh[n * 128 + k]);
}

struct SMem {
    uint4 w1m[4096];           // 65536 B  W1 B-frags, block-resident
    __half dc[4 * 256];        // 2048 B, dc_off swizzle
    float sg[2048];            // 8192 B gates [g][512]
    float se[512];             // 2048 B e partials
    __half spH[512];           // 1024 B p fp16 [g][128]
    __half ctxH[512];          // 1024 B ctx fp16 [g][128] (epilogue)
    __half beta[256];          // 512 B fp16 beta [g][64]
    __half w2h[128];           // 256 B
    float sY[256];             // 1024 B
    float hs[8];               // 32 B  wave partial sums for y~
};                             // 81696 B -> 2 blocks/CU (163392 <= 163840)

__global__ __launch_bounds__(512, 4) void decoder_scan(
    const float* __restrict__ Y, const float* __restrict__ W2,
    const float* __restrict__ Wih, const float* __restrict__ bih,
    const float* __restrict__ bhh, const float* __restrict__ fcW,
    const float* __restrict__ fcb, const float* __restrict__ fcfW,
    const float* __restrict__ fcfb,
    const __half* __restrict__ HWh, const __half* __restrict__ HhT,
    const uint4* __restrict__ W1m4, const uint4* __restrict__ WTm4,
    float* __restrict__ out) {

    __shared__ SMem sm;

    const int tid = threadIdx.x;
    const int bbase = blockIdx.x * G;
    const int g_hi = tid >> 7;          // (g, f) mapping; == wv>>1 per wave pair
    const int f_lo = tid & 127;
    const int lane = tid & 63;
    const int wv = tid >> 6;            // wave 0..7
    const int g2 = tid >> 7;            // ph2 mapping (g, fc, tt)
    const int fc = (tid >> 6) & 1;
    const int tt = tid & 63;

    // ---- init ----
    // W1 B-frags -> LDS (block-resident, conflict-free b128 reads)
    #pragma unroll
    for (int u = 0; u < 8; ++u) sm.w1m[u * 512 + tid] = W1m4[u * 512 + tid];
    // HW[g2][tt][fc*64..+64] slice -> laundered registers (32 VGPR)
    uint4 hwr[8];
    {
        const uint4* src = (const uint4*)(HWh + (((long)(bbase + g2) * 64 + tt) * 128 + fc * 64));
        #pragma unroll
        for (int u = 0; u < 8; ++u) { hwr[u] = src[u]; LAUNDER4(hwr[u]); }
    }
    // H[g][0:64][f] slice -> laundered registers (32 VGPR)
    uint4 hr[8];
    {
        const uint4* src = (const uint4*)(HhT + (((long)(bbase + g_hi) * 128 + f_lo) * 64));
        #pragma unroll
        for (int u = 0; u < 8; ++u) { hr[u] = src[u]; LAUNDER4(hr[u]); }
    }
    ((unsigned*)sm.dc)[tid] = 0u;
    if (tid < 128) sm.w2h[tid] = __float2half(W2[tid]);
    if (tid < 256) sm.sY[tid] = Y[(long)bbase * TN + tid];
    float c_reg = 0.f;
    float wih4[4], bs4[4];
    #pragma unroll
    for (int q = 0; q < 4; ++q) {
        wih4[q] = Wih[q * 128 + f_lo];
        bs4[q] = bih[q * 128 + f_lo] + bhh[q * 128 + f_lo];
    }
    const float fcwf = fcW[f_lo];
    const float fcw2 = fcW[128], fcb0 = fcb[0];
    __syncthreads();

    #pragma unroll 1
    for (int t = 0; t < TN; ++t) {
        // ==== region A: gates = d@WhhT (L2 stream) + p = dc@W1 (LDS) ====
        {
            const int m = lane & 15, q = lane >> 4;
            FU afr[4];
            // A-frag chunk kt 0..3 (c in 0..15 -> slot = c^m)
            #pragma unroll
            for (int kt = 0; kt < 4; ++kt) {
                int c = kt * 4 + q;
                afr[kt].u = *(const uint4*)&sm.dc[m * 256 + (c ^ m) * 8];
            }
            // gates: 4 N-tiles x 4 K-tiles, store each tile immediately
            const uint4* wtg = WTm4 + (size_t)(wv * 16) * 64 + lane;
            #pragma unroll
            for (int i = 0; i < 4; ++i) {
                float4v gacc = (float4v){0.f, 0.f, 0.f, 0.f};
                #pragma unroll
                for (int kt = 0; kt < 4; ++kt) {
                    FU b; b.u = wtg[(i * 4 + kt) * 64];
                    gacc = __builtin_amdgcn_mfma_f32_16x16x32_f16(
                        afr[kt].h8, b.h8, gacc, 0, 0, 0);
                }
                if (lane < 16) {
                    #pragma unroll
                    for (int r = 0; r < 4; ++r)
                        sm.sg[r * 512 + (wv * 4 + i) * 16 + lane] = gacc[r];
                }
            }
            // p: kt 0..3 with current afr, then kt 4..7 with reloaded afr
            float4v pacc = (float4v){0.f, 0.f, 0.f, 0.f};
            #pragma unroll
            for (int kt = 0; kt < 4; ++kt) {
                FU b; b.u = sm.w1m[(wv * 8 + kt) * 64 + lane];
                pacc = __builtin_amdgcn_mfma_f32_16x16x32_f16(
                    afr[kt].h8, b.h8, pacc, 0, 0, 0);
            }
            #pragma unroll
            for (int kt = 0; kt < 4; ++kt) {
                int c = (kt + 4) * 4 + q;   // 16..31
                afr[kt].u = *(const uint4*)&sm.dc[m * 256 + (16 | ((c & 15) ^ m)) * 8];
                FU b; b.u = sm.w1m[(wv * 8 + 4 + kt) * 64 + lane];
                pacc = __builtin_amdgcn_mfma_f32_16x16x32_f16(
                    afr[kt].h8, b.h8, pacc, 0, 0, 0);
            }
            if (lane < 16) {
                #pragma unroll
                for (int r = 0; r < 4; ++r)
                    sm.spH[r * 128 + wv * 16 + lane] = __float2half(pacc[r]);
            }
        }
        __syncthreads();   // b1

        // ==== ph2: e partials (packed fp16 tanh, HW in regs, p broadcast) ====
        {
            const uint4* pH = (const uint4*)&sm.spH[g2 * 128 + fc * 64];
            const __half2* w2b = (const __half2*)&sm.w2h[fc * 64];
            const __half2 kk = __float2half2_rn(-2.88539008f);
            const __half2 one2 = __float2half2_rn(1.f);
            const __half2 two2 = __float2half2_rn(2.f);
            const __half2 none2 = __float2half2_rn(-1.f);
            float ea0 = 0.f, ea1 = 0.f, ea2 = 0.f, ea3 = 0.f;
            #pragma unroll
            for (int u = 0; u < 8; ++u) {
                FU hw; hw.u = hwr[u];
                FU pp; pp.u = pH[u];
                __half2 th0 = tanh2(__hadd2(hw.h2[0], pp.h2[0]), kk, one2, two2, none2);
                __half2 th1 = tanh2(__hadd2(hw.h2[1], pp.h2[1]), kk, one2, two2, none2);
                __half2 th2 = tanh2(__hadd2(hw.h2[2], pp.h2[2]), kk, one2, two2, none2);
                __half2 th3 = tanh2(__hadd2(hw.h2[3], pp.h2[3]), kk, one2, two2, none2);
                ea0 = fdot2f(th0, w2b[u * 4 + 0], ea0);
                ea1 = fdot2f(th1, w2b[u * 4 + 1], ea1);
                ea2 = fdot2f(th2, w2b[u * 4 + 2], ea2);
                ea3 = fdot2f(th3, w2b[u * 4 + 3], ea3);
            }
            sm.se[g2 * 128 + fc * 64 + tt] = (ea0 + ea1) + (ea2 + ea3);
        }
        __syncthreads();   // b2

        // ==== ph3+ph4: softmax (per-wave, redundant per pair) + ctx + hs ====
        {
            float e = sm.se[g_hi * 128 + lane] + sm.se[g_hi * 128 + 64 + lane];
            float ex = __expf(e);   // |e| bounded by sum|W2| ~34, fp32 safe
            float s = ex;
            #pragma unroll
            for (int d = 1; d < 64; d <<= 1) s += __shfl_xor(s, d, 64);
            sm.beta[g_hi * 64 + lane] = __float2half(ex * __builtin_amdgcn_rcpf(s));
            // ctx for own f from hr regs (beta written by same wave: no barrier)
            const uint4* bb = (const uint4*)&sm.beta[g_hi * 64];
            float ca0 = 0.f, ca1 = 0.f;
            #pragma unroll
            for (int u = 0; u < 8; ++u) {
                FU hh; hh.u = hr[u];
                FU bt; bt.u = bb[u];
                ca0 = fdot2f(hh.h2[0], bt.h2[0], ca0);
                ca1 = fdot2f(hh.h2[1], bt.h2[1], ca1);
                ca0 = fdot2f(hh.h2[2], bt.h2[2], ca0);
                ca1 = fdot2f(hh.h2[3], bt.h2[3], ca1);
            }
            float ctx_own = ca0 + ca1;
            sm.ctxH[g_hi * 128 + f_lo] = __float2half(ctx_own);
            float v = ctx_own * fcwf;
            #pragma unroll
            for (int d = 1; d < 64; d <<= 1) v += __shfl_xor(v, d, 64);
            if (lane == 0) sm.hs[wv] = v;
        }
        __syncthreads();   // b3

        // ==== ph5+ph7: y_tilde + LSTM cell ====
        {
            float syg = sm.hs[2 * g_hi] + sm.hs[2 * g_hi + 1]
                      + fmaf(sm.sY[g_hi * 64 + t], fcw2, fcb0);
            float a0 = sm.sg[g_hi * 512 + f_lo]       + fmaf(syg, wih4[0], bs4[0]);
            float a1 = sm.sg[g_hi * 512 + 128 + f_lo] + fmaf(syg, wih4[1], bs4[1]);
            float a2 = sm.sg[g_hi * 512 + 256 + f_lo] + fmaf(syg, wih4[2], bs4[2]);
            float a3 = sm.sg[g_hi * 512 + 384 + f_lo] + fmaf(syg, wih4[3], bs4[3]);
            float ig = fast_sigmoid(a0);
            float fg = fast_sigmoid(a1);
            float gt = fast_tanhf(a2);
            float og = fast_sigmoid(a3);
            c_reg = fmaf(fg, c_reg, ig * gt);
            float dn = og * fast_tanhf(c_reg);
            sm.dc[dc_off(g_hi, f_lo)] = __float2half(dn);
            sm.dc[dc_off(g_hi, 128 + f_lo)] = __float2half(c_reg);
        }
        __syncthreads();   // b4 (step end)
    }

    // ---- epilogue ----
    if (wv < 4) {
        const int g = wv;
        float part = __half2float(sm.dc[dc_off(g, lane)]) * fcfW[lane]
                   + __half2float(sm.dc[dc_off(g, 64 + lane)]) * fcfW[64 + lane]
                   + __half2float(sm.ctxH[g * 128 + lane]) * fcfW[128 + lane]
                   + __half2float(sm.ctxH[g * 128 + 64 + lane]) * fcfW[192 + lane];
        #pragma unroll
        for (int d = 1; d < 64; d <<= 1) part += __shfl_xor(part, d, 64);
        if (lane == 0) out[bbase + g] = part + fcfb[0];
    }
}

extern "C" void kernel_launch(void* const* d_in, const int* in_sizes, int n_in,
                              void* d_out, int out_size, void* d_ws, size_t ws_size,
                              hipStream_t stream) {
    const float* H    = (const float*)d_in[0];
    const float* Y    = (const float*)d_in[1];
    const float* W1   = (const float*)d_in[2];
    const float* b1   = (const float*)d_in[3];
    const float* W2   = (const float*)d_in[4];
    // d_in[5] = attn_b2: softmax-shift-invariant, unused
    const float* Wih  = (const float*)d_in[6];
    const float* Whh  = (const float*)d_in[7];
    const float* bih  = (const float*)d_in[8];
    const float* bhh  = (const float*)d_in[9];
    const float* fcW  = (const float*)d_in[10];
    const float* fcb  = (const float*)d_in[11];
    const float* fcfW = (const float*)d_in[12];
    const float* fcfb = (const float*)d_in[13];

    char* ws = (char*)d_ws;
    __half* HWh = (__half*)ws;                            // 32 MB
    __half* HhT = (__half*)(ws + 33554432);               // 32 MB
    __half* W1m = (__half*)(ws + 2 * 33554432);           // 64 KB
    __half* WTm = (__half*)(ws + 2 * 33554432 + 65536);   // 128 KB
    float* out = (float*)d_out;

    prep_hw<<<BN * TN / 16, 256, 0, stream>>>(H, W1, b1, HWh);
    prep_ht<<<BN, 256, 0, stream>>>(H, HhT);
    prep_w1m<<<128, 256, 0, stream>>>(W1, W1m);
    prep_wtm<<<256, 256, 0, stream>>>(Whh, WTm);
    decoder_scan<<<NBLK, 512, 0, stream>>>(Y, W2, Wih, bih, bhh,
                                           fcW, fcb, fcfW, fcfb,
                                           HWh, HhT, (const uint4*)W1m,
                                           (const uint4*)WTm, out);
}